// Round 3
// baseline (1356.642 us; speedup 1.0000x reference)
//
#include <hip/hip_runtime.h>

#define B_ 64
#define S_ 2048
#define E_ 256
#define H_ 256

typedef _Float16 half2_t __attribute__((ext_vector_type(2)));
typedef _Float16 half4_t __attribute__((ext_vector_type(4)));
typedef _Float16 half8_t __attribute__((ext_vector_type(8)));
typedef float   float4_t __attribute__((ext_vector_type(4)));

#if defined(__has_builtin)
#if __has_builtin(__builtin_amdgcn_fdot2)
#define HAVE_FDOT2 1
#endif
#endif

__device__ __forceinline__ float dot2f(half2_t a, half2_t b, float c) {
#ifdef HAVE_FDOT2
    return __builtin_amdgcn_fdot2(a, b, c, false);
#else
    return c + (float)a[0] * (float)b[0] + (float)a[1] * (float)b[1];
#endif
}

// ---------------------------------------------------------------------------
// Phase 1:  xw[m][n] = sum_k x[m][k] * Ww[n][k] + Wb[n]
//   M = B*S = 131072, N = H = 256 (full width per WG), K = E = 256 (2 halves)
//   f16 MFMA (16x16x32), f32 accumulate. Result written into d_out[0 : B*S*H].
// ---------------------------------------------------------------------------
#define BM   128
#define PADK 136   // 128 + 8 f16 pad -> row stride 68 dwords (2-way = free)

__global__ __launch_bounds__(256, 1)
void phase1_gemm(const float* __restrict__ x, const float* __restrict__ Ww,
                 const float* __restrict__ Wb, float* __restrict__ xw) {
    __shared__ _Float16 Alds[BM * PADK];   //  34816 B
    __shared__ _Float16 Blds[H_ * PADK];   //  69632 B  (total 104448 < 160K)

    const int tid = threadIdx.x;
    const int w   = tid >> 6;     // wave 0..3 -> N quarter
    const int l   = tid & 63;
    const long m0 = (long)blockIdx.x * BM;

    float4_t acc[8][4];
#pragma unroll
    for (int mt = 0; mt < 8; ++mt)
#pragma unroll
        for (int nt = 0; nt < 4; ++nt)
            acc[mt][nt] = (float4_t)(0.f);

    for (int kh = 0; kh < 2; ++kh) {
        __syncthreads();  // protect LDS reuse across kh iterations
        // ---- stage A: 128 rows x 128 k, f32 -> f16 (coalesced float4) ----
#pragma unroll
        for (int i = 0; i < 16; ++i) {
            int idx = i * 256 + tid;          // float4 index in 128x128 block
            int r   = idx >> 5;               // 32 float4 per row
            int k4  = idx & 31;
            float4_t v = *reinterpret_cast<const float4_t*>(
                x + (m0 + r) * E_ + kh * 128 + k4 * 4);
            half4_t h;
            h[0] = (_Float16)v[0]; h[1] = (_Float16)v[1];
            h[2] = (_Float16)v[2]; h[3] = (_Float16)v[3];
            *reinterpret_cast<half4_t*>(&Alds[r * PADK + k4 * 4]) = h;
        }
        // ---- stage B: 256 rows x 128 k of Ww, f32 -> f16 ----
#pragma unroll
        for (int i = 0; i < 32; ++i) {
            int idx = i * 256 + tid;
            int n   = idx >> 5;
            int k4  = idx & 31;
            float4_t v = *reinterpret_cast<const float4_t*>(
                Ww + n * E_ + kh * 128 + k4 * 4);
            half4_t h;
            h[0] = (_Float16)v[0]; h[1] = (_Float16)v[1];
            h[2] = (_Float16)v[2]; h[3] = (_Float16)v[3];
            *reinterpret_cast<half4_t*>(&Blds[n * PADK + k4 * 4]) = h;
        }
        __syncthreads();
        // ---- MFMA: 4 k-steps of 32 ----
#pragma unroll
        for (int ks = 0; ks < 4; ++ks) {
            half8_t a[8], b[4];
#pragma unroll
            for (int mt = 0; mt < 8; ++mt) {
                int row = mt * 16 + (l & 15);
                a[mt] = *reinterpret_cast<const half8_t*>(
                    &Alds[row * PADK + ks * 32 + (l >> 4) * 8]);
            }
#pragma unroll
            for (int nt = 0; nt < 4; ++nt) {
                int col = w * 64 + nt * 16 + (l & 15);
                b[nt] = *reinterpret_cast<const half8_t*>(
                    &Blds[col * PADK + ks * 32 + (l >> 4) * 8]);
            }
#pragma unroll
            for (int mt = 0; mt < 8; ++mt)
#pragma unroll
                for (int nt = 0; nt < 4; ++nt)
                    acc[mt][nt] = __builtin_amdgcn_mfma_f32_16x16x32_f16(
                        a[mt], b[nt], acc[mt][nt], 0, 0, 0);
        }
    }
    // ---- epilogue: + Wb, store f32 (row = (l>>4)*4 + e, col = l&15) ----
#pragma unroll
    for (int nt = 0; nt < 4; ++nt) {
        int col  = w * 64 + nt * 16 + (l & 15);
        float wb = Wb[col];
#pragma unroll
        for (int mt = 0; mt < 8; ++mt)
#pragma unroll
            for (int e = 0; e < 4; ++e) {
                long row = m0 + mt * 16 + (l >> 4) * 4 + e;
                xw[row * H_ + col] = acc[mt][nt][e] + wb;
            }
    }
}

// ---------------------------------------------------------------------------
// Phase 2: per-batch recurrence, one WG (256 threads) per batch, 64 WGs.
//   Thread j owns output row j: Uw[j][*] as 128 half2 in registers, state t_j.
//   Per step: h_j = tanh(xw_j + t_j)  (xw read from d_out, h3 written back
//   over the same element);  t_j = sum_k Uw[j][k] h[k] + Ub[j]  via f16 dot2
//   with h broadcast through a 512B double-buffered LDS buffer.
//   One raw s_barrier + manual lgkmcnt(0) per step (never drains vmcnt, so
//   the 4-deep xw prefetch and the h3 stores stay in flight across steps).
// ---------------------------------------------------------------------------
struct __align__(16) Ch { unsigned v[16]; };   // 32 f16 = one 64B chunk

__device__ __forceinline__ Ch ldch(const _Float16* hb, int c) {
    const uint4* p = reinterpret_cast<const uint4*>(hb + c * 32);
    Ch r;
    uint4* rv = reinterpret_cast<uint4*>(r.v);
    rv[0] = p[0]; rv[1] = p[1]; rv[2] = p[2]; rv[3] = p[3];
    return r;
}

__global__ __launch_bounds__(256, 1)
void scan_kernel(const float* __restrict__ Uw, const float* __restrict__ Ub,
                 float* __restrict__ out /* xw in, h3 out */,
                 float* __restrict__ tfin) {
    __shared__ __align__(16) _Float16 h3[2][H_];   // 1 KB double buffer

    const int b = blockIdx.x;
    const int j = threadIdx.x;

    // ---- load U row j -> 128 half2 registers (f32 -> f16) ----
    half2_t u[128];
    {
        const float4_t* up = reinterpret_cast<const float4_t*>(Uw + (size_t)j * H_);
#pragma unroll
        for (int i = 0; i < 64; ++i) {
            float4_t q = up[i];
            half2_t h01, h23;
            h01[0] = (_Float16)q[0]; h01[1] = (_Float16)q[1];
            h23[0] = (_Float16)q[2]; h23[1] = (_Float16)q[3];
            u[2 * i]     = h01;
            u[2 * i + 1] = h23;
        }
    }
    const float ub = Ub[j];
    float tj = 0.f;

    float* obase = out + (size_t)b * S_ * H_ + j;

    // 4-deep xw prefetch pipeline (covers ~900cy HBM latency; reads past the
    // S_ range land in the t_final / next-batch region of d_out: in-bounds,
    // values discarded).
    float xb[4];
#pragma unroll
    for (int i = 0; i < 4; ++i) xb[i] = obase[(size_t)i * H_];

    for (int t = 0; t < S_; t += 4) {
#pragma unroll
        for (int u4 = 0; u4 < 4; ++u4) {        // static indices after unroll
            const int ts = t + u4;
            float xw_cur = xb[u4];
            xb[u4] = obase[(size_t)(ts + 4) * H_];   // prefetch ts+4

            float s  = xw_cur + tj;
            float e2 = __expf(2.f * s);
            float h  = 1.f - 2.f / (e2 + 1.f);       // tanh(s)

            obase[(size_t)ts * H_] = h;              // h3 overwrites its own xw

            const int cur = ts & 1;
            h3[cur][j] = (_Float16)h;
            // own LDS write visible before anyone reads; do NOT drain vmcnt
            asm volatile("s_waitcnt lgkmcnt(0)" ::: "memory");
            __builtin_amdgcn_s_barrier();
            asm volatile("" ::: "memory");           // pin reads below barrier

            const _Float16* hb = &h3[cur][0];
            float accs[4] = {0.f, 0.f, 0.f, 0.f};
            Ch cc = ldch(hb, 0);
#pragma unroll
            for (int c = 0; c < 8; ++c) {
                Ch nx;
                if (c < 7) nx = ldch(hb, c + 1);
#pragma unroll
                for (int i = 0; i < 16; ++i) {
                    half2_t hv = __builtin_bit_cast(half2_t, cc.v[i]);
                    accs[i & 3] = dot2f(u[c * 16 + i], hv, accs[i & 3]);
                }
                if (c < 7) cc = nx;
            }
            tj = (accs[0] + accs[1]) + (accs[2] + accs[3]) + ub;
        }
    }
    tfin[(size_t)b * H_ + j] = tj;
}

// ---------------------------------------------------------------------------
extern "C" void kernel_launch(void* const* d_in, const int* in_sizes, int n_in,
                              void* d_out, int out_size, void* d_ws, size_t ws_size,
                              hipStream_t stream) {
    const float* x  = (const float*)d_in[0];
    const float* Ww = (const float*)d_in[1];
    const float* Wb = (const float*)d_in[2];
    const float* Uw = (const float*)d_in[3];
    const float* Ub = (const float*)d_in[4];

    float* out  = (float*)d_out;
    float* xw   = out;                              // aliased on purpose
    float* tfin = out + (size_t)B_ * S_ * H_;

    hipLaunchKernelGGL(phase1_gemm, dim3((B_ * S_) / BM), dim3(256), 0, stream,
                       x, Ww, Wb, xw);
    hipLaunchKernelGGL(scan_kernel, dim3(B_), dim3(256), 0, stream,
                       Uw, Ub, xw, tfin);
}